// Round 8
// baseline (865.257 us; speedup 1.0000x reference)
//
#include <hip/hip_runtime.h>
#include <hip/hip_bf16.h>

#define K_PTS 128
#define DIM   512
#define BK    32
#define XS_STRIDE 132   // padded leading dim for transposed staging
#define B_CAP 320       // measured optimum: {128:547, 320:527, 768:646} us

__device__ __forceinline__ int rdlane_i(int v, int lane) {
    return __builtin_amdgcn_readlane(v, lane);
}
__device__ __forceinline__ float rdlane_f(float v, int lane) {
    return __int_as_float(__builtin_amdgcn_readlane(__float_as_int(v), lane));
}
__device__ __forceinline__ void wave_fence() {
    asm volatile("s_waitcnt lgkmcnt(0)" ::: "memory");
}

#define DPP_ID 0xFFFFFFFFu

template <int CTRL, int RM>
__device__ __forceinline__ unsigned dpp_min1(unsigned k) {
    unsigned o = (unsigned)__builtin_amdgcn_update_dpp((int)DPP_ID, (int)k, CTRL, RM, 0xF, false);
    return min(k, o);
}
// min over 64 lanes -> uniform (via lane 63)
__device__ __forceinline__ unsigned wave_min_u32(unsigned k) {
    k = dpp_min1<0x111, 0xF>(k);   // row_shr:1
    k = dpp_min1<0x112, 0xF>(k);   // row_shr:2
    k = dpp_min1<0x114, 0xF>(k);   // row_shr:4
    k = dpp_min1<0x118, 0xF>(k);   // row_shr:8
    k = dpp_min1<0x142, 0xA>(k);   // row_bcast:15 -> rows 1,3
    k = dpp_min1<0x143, 0xC>(k);   // row_bcast:31 -> rows 2,3
    return (unsigned)rdlane_i((int)k, 63);
}
template <int CTRL, int RM>
__device__ __forceinline__ void dpp_min2(unsigned& best, unsigned& sec) {
    unsigned ob = (unsigned)__builtin_amdgcn_update_dpp((int)DPP_ID, (int)best, CTRL, RM, 0xF, false);
    unsigned os = (unsigned)__builtin_amdgcn_update_dpp((int)DPP_ID, (int)sec,  CTRL, RM, 0xF, false);
    sec  = min(max(best, ob), min(sec, os));
    best = min(best, ob);
}
// (min, 2nd-min) over 64 lanes -> uniform pair
__device__ __forceinline__ void wave_min2_u32(unsigned& best, unsigned& sec) {
    dpp_min2<0x111, 0xF>(best, sec);
    dpp_min2<0x112, 0xF>(best, sec);
    dpp_min2<0x114, 0xF>(best, sec);
    dpp_min2<0x118, 0xF>(best, sec);
    dpp_min2<0x142, 0xA>(best, sec);
    dpp_min2<0x143, 0xC>(best, sec);
    best = (unsigned)rdlane_i((int)best, 63);
    sec  = (unsigned)rdlane_i((int)sec, 63);
}

// Register row-gather with STATIC indices only (rule #20): uniform SGPR switch,
// every arr[] access compile-time constant -> SROA keeps slice in VGPRs.
#define GR1(k)  case (k): gr = arr[(k)]; break;
#define GR4(k)  GR1(k) GR1((k)+1) GR1((k)+2) GR1((k)+3)
#define GR16(k) GR4(k) GR4((k)+4) GR4((k)+8) GR4((k)+12)
#define GR64(k) GR16(k) GR16((k)+16) GR16((k)+32) GR16((k)+48)
#define GETROW(dst, idx) do { float2 gr;                      \
    switch (idx) { GR64(0) GR64(64)                           \
        default: gr = make_float2(0.0f, 0.0f); break; }       \
    (dst) = gr; } while (0)

// ============================================================================
// Kernel 1: cost matrices -> global workspace G[b][128][128]
// (phase 1 of the proven baseline, unchanged math; 88 VGPR, full occupancy)
// ============================================================================
__global__ __launch_bounds__(256, 2)
void cost_kernel(const float* __restrict__ X, const float* __restrict__ Y,
                 float* __restrict__ G) {
    const int b = blockIdx.x;
    const int t = threadIdx.x;

    __shared__ float stage[2 * BK * XS_STRIDE];
    __shared__ float sx_sh[K_PTS];
    __shared__ float sy_sh[K_PTS];

    float* Xs = stage;
    float* Ys = stage + BK * XS_STRIDE;

    const float* Xg = X + (size_t)b * K_PTS * DIM;
    const float* Yg = Y + (size_t)b * K_PTS * DIM;
    float* Gb = G + (size_t)b * K_PTS * K_PTS;

    float acc[8][8];
#pragma unroll
    for (int i = 0; i < 8; ++i)
#pragma unroll
        for (int j = 0; j < 8; ++j) acc[i][j] = 0.0f;

    float nrm = 0.0f;
    const int tx = t & 15;
    const int ty = t >> 4;

    for (int k0 = 0; k0 < DIM; k0 += BK) {
        __syncthreads();
#pragma unroll
        for (int i = 0; i < 4; ++i) {
            int idx = t + i * 256;
            int r  = idx >> 3;
            int kq = idx & 7;
            float4 vx = *(const float4*)(Xg + r * DIM + k0 + kq * 4);
            float4 vy = *(const float4*)(Yg + r * DIM + k0 + kq * 4);
            int kb = kq * 4;
            Xs[(kb + 0) * XS_STRIDE + r] = vx.x;
            Xs[(kb + 1) * XS_STRIDE + r] = vx.y;
            Xs[(kb + 2) * XS_STRIDE + r] = vx.z;
            Xs[(kb + 3) * XS_STRIDE + r] = vx.w;
            Ys[(kb + 0) * XS_STRIDE + r] = vy.x;
            Ys[(kb + 1) * XS_STRIDE + r] = vy.y;
            Ys[(kb + 2) * XS_STRIDE + r] = vy.z;
            Ys[(kb + 3) * XS_STRIDE + r] = vy.w;
        }
        __syncthreads();
        for (int kk = 0; kk < BK; ++kk) {
            const float* xrow = Xs + kk * XS_STRIDE;
            const float* yrow = Ys + kk * XS_STRIDE;
            float4 xa = *(const float4*)(xrow + ty * 8);
            float4 xb = *(const float4*)(xrow + ty * 8 + 4);
            float4 ya = *(const float4*)(yrow + tx * 8);
            float4 yb = *(const float4*)(yrow + tx * 8 + 4);
            float av[8] = {xa.x, xa.y, xa.z, xa.w, xb.x, xb.y, xb.z, xb.w};
            float bv[8] = {ya.x, ya.y, ya.z, ya.w, yb.x, yb.y, yb.z, yb.w};
#pragma unroll
            for (int i = 0; i < 8; ++i)
#pragma unroll
                for (int j = 0; j < 8; ++j)
                    acc[i][j] = fmaf(av[i], bv[j], acc[i][j]);
        }
        if (t < 128) {
#pragma unroll
            for (int kk = 0; kk < BK; ++kk) {
                float v = Xs[kk * XS_STRIDE + t];
                nrm = fmaf(v, v, nrm);
            }
        } else {
#pragma unroll
            for (int kk = 0; kk < BK; ++kk) {
                float v = Ys[kk * XS_STRIDE + (t - 128)];
                nrm = fmaf(v, v, nrm);
            }
        }
    }
    if (t < 128) sx_sh[t] = nrm; else sy_sh[t - 128] = nrm;
    __syncthreads();
#pragma unroll
    for (int i = 0; i < 8; ++i) {
        int r = ty * 8 + i;
        float sxr = sx_sh[r];
        float4 o0, o1;
        o0.x = sxr + sy_sh[tx * 8 + 0] - 2.0f * acc[i][0];
        o0.y = sxr + sy_sh[tx * 8 + 1] - 2.0f * acc[i][1];
        o0.z = sxr + sy_sh[tx * 8 + 2] - 2.0f * acc[i][2];
        o0.w = sxr + sy_sh[tx * 8 + 3] - 2.0f * acc[i][3];
        o1.x = sxr + sy_sh[tx * 8 + 4] - 2.0f * acc[i][4];
        o1.y = sxr + sy_sh[tx * 8 + 5] - 2.0f * acc[i][5];
        o1.z = sxr + sy_sh[tx * 8 + 6] - 2.0f * acc[i][6];
        o1.w = sxr + sy_sh[tx * 8 + 7] - 2.0f * acc[i][7];
        *(float4*)&Gb[r * K_PTS + tx * 8]     = o0;
        *(float4*)&Gb[r * K_PTS + tx * 8 + 4] = o1;
    }
}

// ============================================================================
// Kernel 2: LAPJV, one wave per batch, cost slice register-resident.
// 64 threads/block, launch_bounds(64,1) -> 512-VGPR budget; ~3.6KB LDS.
// Pop chain: reduce -> readlane -> SGPR-switch gather (~50cy) -> relax
// (the 120cy LDS read is gone from the serial chain).
// ============================================================================
__global__ __launch_bounds__(64, 1)
void lap_kernel(const float* __restrict__ G, float* __restrict__ out,
                float inv_total) {
    const int b = blockIdx.x;
    const int t = threadIdx.x;

    __shared__ float sx_sh[K_PTS];
    __shared__ float sy_sh[K_PTS];
    __shared__ float u_sh[K_PTS];
    __shared__ int   rmatch[K_PTS];
    __shared__ int   wl[512];
    __shared__ int   wl_n;

    const float*  Gb  = G + (size_t)b * K_PTS * K_PTS;
    const float2* Gb2 = (const float2*)Gb;
    const int c0 = 2 * t, c1 = 2 * t + 1;

    asm volatile("s_setprio 3");

    // --- load this lane's column-pair slice into registers (static indices) ---
    float2 arr[128];
#pragma unroll
    for (int r = 0; r < 128; ++r) arr[r] = Gb2[r * 64 + t];

    u_sh[t] = 0.0f; u_sh[t + 64] = 0.0f;
    rmatch[t] = -1; rmatch[t + 64] = -1;
    wave_fence();

    float v0, v1;
    int p_lo = -1, p_hi = -1;

    // --- A) column reduction (pure register scan) ---
    {
        float m0 = 1e30f, m1 = 1e30f;
        int a0 = 0, a1 = 0;
#pragma unroll
        for (int i = 0; i < 128; ++i) {
            if (arr[i].x < m0) { m0 = arr[i].x; a0 = i; }
            if (arr[i].y < m1) { m1 = arr[i].y; a1 = i; }
        }
        v0 = m0; v1 = m1;
        int w0 = atomicCAS(&rmatch[a0], -1, c0);
        if (w0 == -1) p_lo = a0;
        int w1 = atomicCAS(&rmatch[a1], -1, c1);
        if (w1 == -1) p_hi = a1;
    }
    wave_fence();

    // --- A2) reduction transfer (row-parallel; rows stream from global/L2) ---
    *(float2*)&sy_sh[c0] = make_float2(v0, v1);
    wave_fence();
#pragma unroll
    for (int which = 0; which < 2; ++which) {
        int i  = t + which * 64;
        int j1 = rmatch[i];
        float mu = 1e30f;
        if (j1 >= 0) {
#pragma unroll 4
            for (int s = 0; s < 64; ++s) {
                int jj = (s + t) & 63;
                float2 cc = Gb2[i * 64 + jj];
                float2 vv = *(const float2*)&sy_sh[2 * jj];
                float r0 = cc.x - vv.x;
                float r1 = cc.y - vv.y;
                if (2 * jj     != j1) mu = fminf(mu, r0);
                if (2 * jj + 1 != j1) mu = fminf(mu, r1);
            }
        }
        sx_sh[i] = mu;
    }
    wave_fence();
    if (p_lo >= 0) { float mu = sx_sh[p_lo]; v0 = Gb[p_lo * K_PTS + c0] - mu; u_sh[p_lo] = mu; }
    if (p_hi >= 0) { float mu = sx_sh[p_hi]; v1 = Gb[p_hi * K_PTS + c1] - mu; u_sh[p_hi] = mu; }
    wave_fence();

    // --- worklist of free rows ---
    if (t == 0) {
        int n = 0;
        for (int i = 0; i < K_PTS; ++i) if (rmatch[i] < 0) wl[n++] = i;
        wl_n = n;
    }
    wave_fence();

    // --- B) augmenting row reduction (capped); rows from registers ---
    {
        int head = 0, tail = wl_n, steps = 0;
        while (head < tail && steps < B_CAP) {
            ++steps;
            int i = __builtin_amdgcn_readfirstlane(wl[head++]);
            float2 cc; GETROW(cc, i);
            float r0 = fmaxf(cc.x - v0, 0.0f);
            float r1 = fmaxf(cc.y - v1, 0.0f);
            unsigned k0 = (__float_as_uint(r0) & 0xFFFFFF80u) | (unsigned)c0;
            unsigned k1 = (__float_as_uint(r1) & 0xFFFFFF80u) | (unsigned)c1;
            unsigned best = min(k0, k1), sec = max(k0, k1);
            wave_min2_u32(best, sec);
            int j1 = (int)(best & 127u);
            int j2 = (int)(sec & 127u);
            float mu = __uint_as_float(best & 0xFFFFFF80u);   // 128-ulp truncation: within tolerance
            float nu = __uint_as_float(sec  & 0xFFFFFF80u);
            if (t == 0) u_sh[i] = nu;
            int kO = rdlane_i((j1 & 1) ? p_hi : p_lo, j1 >> 1);
            bool strict = (mu < nu);
            if (strict && t == (j1 >> 1)) {
                float d = nu - mu;
                if (j1 & 1) v1 -= d; else v0 -= d;
            }
            int jA = j1;
            if (!strict && kO >= 0) {
                int k2 = rdlane_i((j2 & 1) ? p_hi : p_lo, j2 >> 1);
                if (k2 < 0) jA = j2;
            }
            int kOld = rdlane_i((jA & 1) ? p_hi : p_lo, jA >> 1);
            if (t == (jA >> 1)) { if (jA & 1) p_hi = i; else p_lo = i; }
            if (t == 0) {
                rmatch[i] = jA;
                if (kOld >= 0) { rmatch[kOld] = -1; wl[tail] = kOld; }
            }
            if (kOld >= 0) ++tail;
            wave_fence();
        }
    }

    // --- rebuild free-row list ---
    if (t == 0) {
        int n = 0;
        for (int i = 0; i < K_PTS; ++i) if (rmatch[i] < 0) wl[n++] = i;
        wl_n = n;
    }
    wave_fence();
    const int nfree = wl_n;

    // --- C) shortest augmenting path; row gathers from registers ---
    for (int idx = 0; idx < nfree; ++idx) {
        int row = __builtin_amdgcn_readfirstlane(wl[idx]);
        float u_lo_reg = u_sh[t];
        float u_hi_reg = u_sh[t + 64];
        float u_row = u_sh[row];            // same-address broadcast read (exact)
        float2 rc; GETROW(rc, row);
        float dist0 = fmaxf(rc.x - u_row - v0, 0.0f);
        float dist1 = fmaxf(rc.y - u_row - v1, 0.0f);
        int way0 = 128, way1 = 128;
        bool sc0 = false, sc1 = false;
        int j1 = 0;
        float D = 0.0f;

        while (true) {
            unsigned k0 = sc0 ? 0xFFFFFFFFu
                              : ((__float_as_uint(dist0) & 0xFFFFFF80u) | (unsigned)c0);
            unsigned k1 = sc1 ? 0xFFFFFFFFu
                              : ((__float_as_uint(dist1) & 0xFFFFFF80u) | (unsigned)c1);
            unsigned k = wave_min_u32(min(k0, k1));
            j1 = (int)(k & 127u);
            D  = __uint_as_float(k & 0xFFFFFF80u);
            int i1 = rdlane_i((j1 & 1) ? p_hi : p_lo, j1 >> 1);
            if (i1 < 0) break;

            if (j1 == c0) sc0 = true;
            if (j1 == c1) sc1 = true;

            float u_i1 = rdlane_f((i1 >= 64) ? u_hi_reg : u_lo_reg, i1 & 63);
            float2 aa; GETROW(aa, i1);          // register gather, no LDS/VMEM latency
            float base = D - u_i1;
            if (!sc0) {
                float cv = fmaxf((aa.x - v0) + base, 0.0f);
                if (cv < dist0) { dist0 = cv; way0 = j1; }
            }
            if (!sc1) {
                float cv = fmaxf((aa.y - v1) + base, 0.0f);
                if (cv < dist1) { dist1 = cv; way1 = j1; }
            }
        }

        if (sc0) { float del = D - dist0; v0 -= del; u_sh[p_lo] += del; }
        if (sc1) { float del = D - dist1; v1 -= del; u_sh[p_hi] += del; }
        if (t == 0) u_sh[row] += D;

        int j0 = j1;
        while (true) {
            int lane0 = j0 >> 1;
            bool odd = (j0 & 1) != 0;
            int jp = rdlane_i(odd ? way1 : way0, lane0);
            int pv;
            if (jp == 128) pv = row;
            else           pv = rdlane_i((jp & 1) ? p_hi : p_lo, jp >> 1);
            if (!odd && lane0 == t) p_lo = pv;
            if ( odd && lane0 == t) p_hi = pv;
            if (jp == 128) break;
            j0 = jp;
        }
        wave_fence();
    }

    // --- total optimal cost (divergent rows -> global gather, once) ---
    float tsum = Gb[p_lo * K_PTS + c0] + Gb[p_hi * K_PTS + c1];
#pragma unroll
    for (int m = 1; m <= 32; m <<= 1)
        tsum += __shfl_xor(tsum, m, 64);
    if (t == 0) atomicAdd(out, tsum * inv_total);
}

// ============================================================================
// Fallback (workspace too small): the measured-527us single-kernel baseline.
// ============================================================================
__global__ __launch_bounds__(256, 2)
void hungarian_mse_fallback(const float* __restrict__ X, const float* __restrict__ Y,
                            float* __restrict__ out, float inv_total) {
    const int b = blockIdx.x;
    const int t = threadIdx.x;

    __shared__ float A[K_PTS * K_PTS];
    __shared__ float sx_sh[K_PTS];
    __shared__ float sy_sh[K_PTS];
    __shared__ float u_sh[K_PTS];
    __shared__ int   rmatch[K_PTS];
    __shared__ int   wl[512];
    __shared__ int   wl_n;

    float* Xs = A;
    float* Ys = A + BK * XS_STRIDE;

    const float* Xg = X + (size_t)b * K_PTS * DIM;
    const float* Yg = Y + (size_t)b * K_PTS * DIM;

    float acc[8][8];
#pragma unroll
    for (int i = 0; i < 8; ++i)
#pragma unroll
        for (int j = 0; j < 8; ++j) acc[i][j] = 0.0f;

    float nrm = 0.0f;
    const int tx = t & 15;
    const int ty = t >> 4;

    for (int k0 = 0; k0 < DIM; k0 += BK) {
        __syncthreads();
#pragma unroll
        for (int i = 0; i < 4; ++i) {
            int idx = t + i * 256;
            int r  = idx >> 3;
            int kq = idx & 7;
            float4 vx = *(const float4*)(Xg + r * DIM + k0 + kq * 4);
            float4 vy = *(const float4*)(Yg + r * DIM + k0 + kq * 4);
            int kb = kq * 4;
            Xs[(kb + 0) * XS_STRIDE + r] = vx.x;
            Xs[(kb + 1) * XS_STRIDE + r] = vx.y;
            Xs[(kb + 2) * XS_STRIDE + r] = vx.z;
            Xs[(kb + 3) * XS_STRIDE + r] = vx.w;
            Ys[(kb + 0) * XS_STRIDE + r] = vy.x;
            Ys[(kb + 1) * XS_STRIDE + r] = vy.y;
            Ys[(kb + 2) * XS_STRIDE + r] = vy.z;
            Ys[(kb + 3) * XS_STRIDE + r] = vy.w;
        }
        __syncthreads();
        for (int kk = 0; kk < BK; ++kk) {
            const float* xrow = Xs + kk * XS_STRIDE;
            const float* yrow = Ys + kk * XS_STRIDE;
            float4 xa = *(const float4*)(xrow + ty * 8);
            float4 xb = *(const float4*)(xrow + ty * 8 + 4);
            float4 ya = *(const float4*)(yrow + tx * 8);
            float4 yb = *(const float4*)(yrow + tx * 8 + 4);
            float av[8] = {xa.x, xa.y, xa.z, xa.w, xb.x, xb.y, xb.z, xb.w};
            float bv[8] = {ya.x, ya.y, ya.z, ya.w, yb.x, yb.y, yb.z, yb.w};
#pragma unroll
            for (int i = 0; i < 8; ++i)
#pragma unroll
                for (int j = 0; j < 8; ++j)
                    acc[i][j] = fmaf(av[i], bv[j], acc[i][j]);
        }
        if (t < 128) {
#pragma unroll
            for (int kk = 0; kk < BK; ++kk) {
                float v = Xs[kk * XS_STRIDE + t];
                nrm = fmaf(v, v, nrm);
            }
        } else {
#pragma unroll
            for (int kk = 0; kk < BK; ++kk) {
                float v = Ys[kk * XS_STRIDE + (t - 128)];
                nrm = fmaf(v, v, nrm);
            }
        }
    }
    if (t < 128) sx_sh[t] = nrm; else sy_sh[t - 128] = nrm;
    if (t < 128) u_sh[t] = 0.0f;
    __syncthreads();
#pragma unroll
    for (int i = 0; i < 8; ++i) {
        int r = ty * 8 + i;
        float sxr = sx_sh[r];
        float4 o0, o1;
        o0.x = sxr + sy_sh[tx * 8 + 0] - 2.0f * acc[i][0];
        o0.y = sxr + sy_sh[tx * 8 + 1] - 2.0f * acc[i][1];
        o0.z = sxr + sy_sh[tx * 8 + 2] - 2.0f * acc[i][2];
        o0.w = sxr + sy_sh[tx * 8 + 3] - 2.0f * acc[i][3];
        o1.x = sxr + sy_sh[tx * 8 + 4] - 2.0f * acc[i][4];
        o1.y = sxr + sy_sh[tx * 8 + 5] - 2.0f * acc[i][5];
        o1.z = sxr + sy_sh[tx * 8 + 6] - 2.0f * acc[i][6];
        o1.w = sxr + sy_sh[tx * 8 + 7] - 2.0f * acc[i][7];
        *(float4*)&A[r * K_PTS + tx * 8]     = o0;
        *(float4*)&A[r * K_PTS + tx * 8 + 4] = o1;
    }
    __syncthreads();

    if (t < 64) {
        asm volatile("s_setprio 3");
        const int c0 = 2 * t, c1 = 2 * t + 1;
        float v0, v1;
        int p_lo = -1, p_hi = -1;

        rmatch[t] = -1; rmatch[t + 64] = -1;
        wave_fence();
        {
            float m0 = 1e30f, m1 = 1e30f;
            int a0 = 0, a1 = 0;
#pragma unroll 4
            for (int i = 0; i < K_PTS; ++i) {
                float2 cc = *(const float2*)&A[i * K_PTS + c0];
                if (cc.x < m0) { m0 = cc.x; a0 = i; }
                if (cc.y < m1) { m1 = cc.y; a1 = i; }
            }
            v0 = m0; v1 = m1;
            int w0 = atomicCAS(&rmatch[a0], -1, c0);
            if (w0 == -1) p_lo = a0;
            int w1 = atomicCAS(&rmatch[a1], -1, c1);
            if (w1 == -1) p_hi = a1;
        }
        wave_fence();

        *(float2*)&sy_sh[c0] = make_float2(v0, v1);
        wave_fence();
#pragma unroll
        for (int which = 0; which < 2; ++which) {
            int i  = t + which * 64;
            int j1 = rmatch[i];
            float mu = 1e30f;
            if (j1 >= 0) {
#pragma unroll 4
                for (int s = 0; s < 64; ++s) {
                    int jj = (s + t) & 63;
                    float2 cc = *(const float2*)&A[i * K_PTS + 2 * jj];
                    float2 vv = *(const float2*)&sy_sh[2 * jj];
                    float r0 = cc.x - vv.x;
                    float r1 = cc.y - vv.y;
                    if (2 * jj     != j1) mu = fminf(mu, r0);
                    if (2 * jj + 1 != j1) mu = fminf(mu, r1);
                }
            }
            sx_sh[i] = mu;
        }
        wave_fence();
        if (p_lo >= 0) { float mu = sx_sh[p_lo]; v0 = A[p_lo * K_PTS + c0] - mu; u_sh[p_lo] = mu; }
        if (p_hi >= 0) { float mu = sx_sh[p_hi]; v1 = A[p_hi * K_PTS + c1] - mu; u_sh[p_hi] = mu; }
        wave_fence();

        if (t == 0) {
            int n = 0;
            for (int i = 0; i < K_PTS; ++i) if (rmatch[i] < 0) wl[n++] = i;
            wl_n = n;
        }
        wave_fence();

        {
            int head = 0, tail = wl_n, steps = 0;
            while (head < tail && steps < B_CAP) {
                ++steps;
                int i = wl[head++];
                float2 cc = *(const float2*)&A[i * K_PTS + c0];
                float r0 = fmaxf(cc.x - v0, 0.0f);
                float r1 = fmaxf(cc.y - v1, 0.0f);
                unsigned k0 = (__float_as_uint(r0) & 0xFFFFFF80u) | (unsigned)c0;
                unsigned k1 = (__float_as_uint(r1) & 0xFFFFFF80u) | (unsigned)c1;
                unsigned best = min(k0, k1), sec = max(k0, k1);
                wave_min2_u32(best, sec);
                int j1 = (int)(best & 127u);
                int j2 = (int)(sec & 127u);
                float mu = __uint_as_float(best & 0xFFFFFF80u);
                float nu = __uint_as_float(sec  & 0xFFFFFF80u);
                if (t == 0) u_sh[i] = nu;
                int kO = rdlane_i((j1 & 1) ? p_hi : p_lo, j1 >> 1);
                bool strict = (mu < nu);
                if (strict && t == (j1 >> 1)) {
                    float d = nu - mu;
                    if (j1 & 1) v1 -= d; else v0 -= d;
                }
                int jA = j1;
                if (!strict && kO >= 0) {
                    int k2 = rdlane_i((j2 & 1) ? p_hi : p_lo, j2 >> 1);
                    if (k2 < 0) jA = j2;
                }
                int kOld = rdlane_i((jA & 1) ? p_hi : p_lo, jA >> 1);
                if (t == (jA >> 1)) { if (jA & 1) p_hi = i; else p_lo = i; }
                if (t == 0) {
                    rmatch[i] = jA;
                    if (kOld >= 0) { rmatch[kOld] = -1; wl[tail] = kOld; }
                }
                if (kOld >= 0) ++tail;
                wave_fence();
            }
        }

        if (t == 0) {
            int n = 0;
            for (int i = 0; i < K_PTS; ++i) if (rmatch[i] < 0) wl[n++] = i;
            wl_n = n;
        }
        wave_fence();
        const int nfree = wl_n;

        for (int idx = 0; idx < nfree; ++idx) {
            int row = wl[idx];
            float u_lo_reg = u_sh[t];
            float u_hi_reg = u_sh[t + 64];
            float u_row = u_sh[row];
            float2 rc = *(const float2*)&A[row * K_PTS + c0];
            float dist0 = fmaxf(rc.x - u_row - v0, 0.0f);
            float dist1 = fmaxf(rc.y - u_row - v1, 0.0f);
            int way0 = 128, way1 = 128;
            bool sc0 = false, sc1 = false;
            int j1 = 0;
            float D = 0.0f;

            while (true) {
                unsigned k0 = sc0 ? 0xFFFFFFFFu
                                  : ((__float_as_uint(dist0) & 0xFFFFFF80u) | (unsigned)c0);
                unsigned k1 = sc1 ? 0xFFFFFFFFu
                                  : ((__float_as_uint(dist1) & 0xFFFFFF80u) | (unsigned)c1);
                unsigned k = wave_min_u32(min(k0, k1));
                j1 = (int)(k & 127u);
                D  = __uint_as_float(k & 0xFFFFFF80u);
                int i1 = rdlane_i((j1 & 1) ? p_hi : p_lo, j1 >> 1);
                if (i1 < 0) break;

                if (j1 == c0) sc0 = true;
                if (j1 == c1) sc1 = true;

                float u_i1 = rdlane_f((i1 >= 64) ? u_hi_reg : u_lo_reg, i1 & 63);
                float2 aa = *(const float2*)&A[i1 * K_PTS + c0];
                float base = D - u_i1;
                if (!sc0) {
                    float cv = fmaxf((aa.x - v0) + base, 0.0f);
                    if (cv < dist0) { dist0 = cv; way0 = j1; }
                }
                if (!sc1) {
                    float cv = fmaxf((aa.y - v1) + base, 0.0f);
                    if (cv < dist1) { dist1 = cv; way1 = j1; }
                }
            }

            if (sc0) { float del = D - dist0; v0 -= del; u_sh[p_lo] += del; }
            if (sc1) { float del = D - dist1; v1 -= del; u_sh[p_hi] += del; }
            if (t == 0) u_sh[row] += D;

            int j0 = j1;
            while (true) {
                int lane0 = j0 >> 1;
                bool odd = (j0 & 1) != 0;
                int jp = rdlane_i(odd ? way1 : way0, lane0);
                int pv;
                if (jp == 128) pv = row;
                else           pv = rdlane_i((jp & 1) ? p_hi : p_lo, jp >> 1);
                if (!odd && lane0 == t) p_lo = pv;
                if ( odd && lane0 == t) p_hi = pv;
                if (jp == 128) break;
                j0 = jp;
            }
            wave_fence();
        }

        float tsum = A[p_lo * K_PTS + c0] + A[p_hi * K_PTS + c1];
#pragma unroll
        for (int m = 1; m <= 32; m <<= 1)
            tsum += __shfl_xor(tsum, m, 64);
        if (t == 0) atomicAdd(out, tsum * inv_total);
    }
}

extern "C" void kernel_launch(void* const* d_in, const int* in_sizes, int n_in,
                              void* d_out, int out_size, void* d_ws, size_t ws_size,
                              hipStream_t stream) {
    const float* X = (const float*)d_in[0];
    const float* Y = (const float*)d_in[1];
    float* out = (float*)d_out;

    const int total = in_sizes[0];              // B*K*D
    const int B = total / (K_PTS * DIM);
    const float inv_total = 1.0f / (float)total;

    hipMemsetAsync(out, 0, out_size * sizeof(float), stream);

    const size_t need = (size_t)B * K_PTS * K_PTS * sizeof(float);
    if (d_ws != nullptr && ws_size >= need) {
        float* G = (float*)d_ws;
        cost_kernel<<<dim3(B), dim3(256), 0, stream>>>(X, Y, G);
        lap_kernel<<<dim3(B), dim3(64), 0, stream>>>(G, out, inv_total);
    } else {
        hungarian_mse_fallback<<<dim3(B), dim3(256), 0, stream>>>(X, Y, out, inv_total);
    }
}